// Round 9
// baseline (653.607 us; speedup 1.0000x reference)
//
#include <hip/hip_runtime.h>

typedef _Float16 f16;
typedef unsigned int uint;
typedef f16 f16x2 __attribute__((ext_vector_type(2)));
typedef f16 f16x8 __attribute__((ext_vector_type(8)));
typedef __fp16 h16x2 __attribute__((ext_vector_type(2)));
typedef float f32x4 __attribute__((ext_vector_type(4)));

#define Bn 512
#define Ln 128
#define Dn 128
#define Cn 512   // 4 gates * D
#define CH 8     // timesteps per chunk
#define NCH 16   // chunks
#define XP 132   // padded row stride for f32 LDS rows

__device__ __forceinline__ float fdot2f(uint a, uint b, float c) {
#if __has_builtin(__builtin_amdgcn_fdot2)
  return __builtin_amdgcn_fdot2(__builtin_bit_cast(f16x2, a),
                                __builtin_bit_cast(f16x2, b), c, false);
#else
  f16x2 av = __builtin_bit_cast(f16x2, a), bv = __builtin_bit_cast(f16x2, b);
  return c + (float)av[0] * (float)bv[0] + (float)av[1] * (float)bv[1];
#endif
}

__device__ __forceinline__ uint pk2(float a, float b) {
#if __has_builtin(__builtin_amdgcn_cvt_pkrtz)
  h16x2 v = __builtin_amdgcn_cvt_pkrtz(a, b);
  return __builtin_bit_cast(uint, v);
#else
  f16x2 v; v[0] = (f16)a; v[1] = (f16)b;
  return __builtin_bit_cast(uint, v);
#endif
}

// ---------------- convert: W -> MFMA-fragment-ordered f16 (WhF), R -> transposed f16 ----------------
__global__ __launch_bounds__(256) void k_convert(const float* __restrict__ Wg,
                                                 const float* __restrict__ Rg,
                                                 f16* __restrict__ WhF,
                                                 f16* __restrict__ RT) {
  int i = blockIdx.x * 256 + threadIdx.x;
  const int nWfrag = 2 * 4 * 32 * 64;   // 16384 groups of 8 f16
  if (i < nWfrag) {
    int lane = i & 63;
    int ii   = (i >> 6) & 31;
    int kk   = (i >> 11) & 3;
    int l    = i >> 13;
    int c = ii * 16 + (lane & 15);
    int d = kk * 32 + ((lane >> 4) << 3);
    const float* src = Wg + ((size_t)(l * 512 + c) * 128 + d);
    f16* dst = WhF + (size_t)i * 8;
    #pragma unroll
    for (int j = 0; j < 8; ++j) dst[j] = (f16)src[j];
  } else {
    int j = i - nWfrag;  // 32768 = 2*4*4*32*32
    if (j < 32768) {
      int dd = j & 31;
      int e  = (j >> 5) & 31;
      int hh = (j >> 10) & 3;
      int g  = (j >> 12) & 3;
      int l  = j >> 14;
      RT[j] = (f16)Rg[((((l * 4 + g) * 4 + hh) * 32 + dd) * 32) + e];
    }
  }
}

// ---------------- fully-fused per-sequence pipeline, all-LDS, wave-specialized ----------------
// 512 blocks x 512 threads. Block = 1 sequence, 8 waves:
//   w0-1: embed+LN0+GEMM0 (chunk p)      -> preA0/preB0, x0s
//   w2-3: LN1+GEMM1       (chunk p-2)    -> preA1/preB1   (reads x1s)
//   w4-5: scan0           (chunk p-1)    -> x1s           (reads pre0, x0s)
//   w6-7: scan1           (chunk p-3)    -> psum/pooled   (reads pre1, x1s)
// All chunk tensors live in LDS (double/triple buffered). Global traffic:
// emb gather + ids + weights + pooled only.
__global__ __launch_bounds__(512, 4) void k_fused(const int* __restrict__ ids,
                                                  const float* __restrict__ emb,
                                                  const float* __restrict__ lnw,
                                                  const float* __restrict__ lnb,
                                                  const f16* __restrict__ WhF,
                                                  const f16* __restrict__ RT,
                                                  const float* __restrict__ bg,
                                                  const float* __restrict__ gnw,
                                                  float* __restrict__ pooled) {
  __shared__ __align__(16) uint  preA0[2][CH * 128];
  __shared__ __align__(16) uint  preB0[2][CH * 128];
  __shared__ __align__(16) uint  preA1[2][CH * 128];
  __shared__ __align__(16) uint  preB1[2][CH * 128];
  __shared__ __align__(16) float x0s[2][CH * XP];
  __shared__ __align__(16) float x1s[3][CH * XP];
  __shared__ __align__(16) f16   hsh0[2][64];
  __shared__ __align__(16) f16   hsh1[2][64];

  const int tid = threadIdx.x;
  const int wv = tid >> 6;
  const int lane = tid & 63;
  const int b = blockIdx.x;

  // scan-role persistent state
  float cc = 0.f, nc = 0.f, mc = 0.f, psum = 0.f;
  float hprev = 0.f, xprev = 0.f;

  if (wv == 4 || wv == 5) hsh0[wv & 1][lane] = (f16)0.f;
  if (wv == 6 || wv == 7) hsh1[wv & 1][lane] = (f16)0.f;

  // ---------------- producer: LN + GEMM for one chunk ----------------
  // layer: 0 (source = emb gather) or 1 (source = x1s chunk). nw = N-half.
  auto gemm_do = [&](int c, int layer, int nw) {
    const int l16 = lane & 15, quad = lane >> 4;
    const int trow = l16 & 7;           // source row in chunk (rows 8-15 dup)
    float v[4][8];
    float s1 = 0.f, s2 = 0.f;
    if (layer == 0) {
      int id = ids[b * Ln + c * CH + trow];
      const float* src = emb + (size_t)id * Dn;
      #pragma unroll
      for (int kk = 0; kk < 4; ++kk) {
        float4 f0 = *(const float4*)(src + kk * 32 + quad * 8);
        float4 f1 = *(const float4*)(src + kk * 32 + quad * 8 + 4);
        v[kk][0]=f0.x; v[kk][1]=f0.y; v[kk][2]=f0.z; v[kk][3]=f0.w;
        v[kk][4]=f1.x; v[kk][5]=f1.y; v[kk][6]=f1.z; v[kk][7]=f1.w;
      }
    } else {
      const float* src = &x1s[c % 3][trow * XP];
      #pragma unroll
      for (int kk = 0; kk < 4; ++kk) {
        float4 f0 = *(const float4*)(src + kk * 32 + quad * 8);
        float4 f1 = *(const float4*)(src + kk * 32 + quad * 8 + 4);
        v[kk][0]=f0.x; v[kk][1]=f0.y; v[kk][2]=f0.z; v[kk][3]=f0.w;
        v[kk][4]=f1.x; v[kk][5]=f1.y; v[kk][6]=f1.z; v[kk][7]=f1.w;
      }
    }
    #pragma unroll
    for (int kk = 0; kk < 4; ++kk)
      #pragma unroll
      for (int j = 0; j < 8; ++j) { s1 += v[kk][j]; s2 += v[kk][j] * v[kk][j]; }
    s1 += __shfl_xor(s1, 16); s2 += __shfl_xor(s2, 16);
    s1 += __shfl_xor(s1, 32); s2 += __shfl_xor(s2, 32);
    float mu = s1 * (1.f / 128.f);
    float rs = rsqrtf(s2 * (1.f / 128.f) - mu * mu + 1e-5f);

    if (layer == 0 && nw == 0 && l16 < 8) {   // stash residual chunk
      float* dst = &x0s[c & 1][trow * XP];
      #pragma unroll
      for (int kk = 0; kk < 4; ++kk) {
        *(float4*)(dst + kk * 32 + quad * 8)     = make_float4(v[kk][0], v[kk][1], v[kk][2], v[kk][3]);
        *(float4*)(dst + kk * 32 + quad * 8 + 4) = make_float4(v[kk][4], v[kk][5], v[kk][6], v[kk][7]);
      }
    }

    const float* lwp = lnw + layer * Dn;
    const float* lbp = lnb + layer * Dn;
    f16x8 a[4];
    #pragma unroll
    for (int kk = 0; kk < 4; ++kk) {
      int k0 = kk * 32 + quad * 8;
      #pragma unroll
      for (int j = 0; j < 8; ++j)
        a[kk][j] = (f16)((v[kk][j] - mu) * rs * lwp[k0 + j] + lbp[k0 + j]);
    }

    f32x4 acc[16] = {};
    const f16* bbase = WhF + (size_t)layer * 65536 + (size_t)lane * 8;
    #pragma unroll
    for (int kk = 0; kk < 4; ++kk) {
      #pragma unroll
      for (int i = 0; i < 16; ++i) {
        f16x8 bf = *(const f16x8*)(bbase + (size_t)(kk * 32 + nw * 16 + i) * 512);
        acc[i] = __builtin_amdgcn_mfma_f32_16x16x32_f16(a[kk], bf, acc[i], 0, 0, 0);
      }
    }
    const float* bias = bg + layer * Cn;
    float bv[16];
    #pragma unroll
    for (int i = 0; i < 16; ++i) bv[i] = bias[(nw * 16 + i) * 16 + l16];
    uint* outP = (layer == 0) ? (nw ? &preB0[c & 1][0] : &preA0[c & 1][0])
                              : (nw ? &preB1[c & 1][0] : &preA1[c & 1][0]);
    if (quad < 2) {
      #pragma unroll
      for (int r = 0; r < 4; ++r) {
        int t = quad * 4 + r;
        #pragma unroll
        for (int i7 = 0; i7 < 8; ++i7)
          outP[t * 128 + i7 * 16 + l16] = pk2(acc[i7][r] + bv[i7], acc[i7 + 8][r] + bv[i7 + 8]);
      }
    }
  };

  // ---------------- consumer: scan one chunk (r6 body, LDS-only) ----------------
  auto scan_do = [&](int c, int layer) {
    const int d = (wv & 1) * 64 + lane;
    const int eo = d & 31;
    const int half = lane >> 5;
    const int headg = (wv & 1) * 2 + half;
    const uint one2 = 0x3C003C00u;
    f16 (*hshL)[64] = layer ? hsh1 : hsh0;
    const int w2 = wv & 1;

    // rr reloaded per phase (keeps static VGPR down); RT is L2-resident.
    uint rr[4][16];
    const uint* RT32 = (const uint*)(RT + layer * 16384);
    #pragma unroll
    for (int g = 0; g < 4; ++g) {
      const uint4* p = (const uint4*)(RT32 + ((g * 4 + headg) * 32 + eo) * 16);
      uint4 q0 = p[0], q1 = p[1], q2 = p[2], q3 = p[3];
      rr[g][0]=q0.x; rr[g][1]=q0.y; rr[g][2]=q0.z; rr[g][3]=q0.w;
      rr[g][4]=q1.x; rr[g][5]=q1.y; rr[g][6]=q1.z; rr[g][7]=q1.w;
      rr[g][8]=q2.x; rr[g][9]=q2.y; rr[g][10]=q2.z; rr[g][11]=q2.w;
      rr[g][12]=q3.x; rr[g][13]=q3.y; rr[g][14]=q3.z; rr[g][15]=q3.w;
    }
    const float gw = gnw[layer * Dn + d];

    const uint* pA = layer ? &preA1[c & 1][0] : &preA0[c & 1][0];
    const uint* pB = layer ? &preB1[c & 1][0] : &preB0[c & 1][0];
    const float* xr = layer ? &x1s[c % 3][0] : &x0s[c & 1][0];
    float* xw = layer ? nullptr : &x1s[c % 3][0];

    uint pa[CH], pb[CH];
    #pragma unroll
    for (int k = 0; k < CH; ++k) { pa[k] = pA[k * 128 + d]; pb[k] = pB[k * 128 + d]; }
    float xcur = xr[d];

    #pragma unroll
    for (int k = 0; k < CH; ++k) {
      uint hu[16];
      {
        const uint* hp = (const uint*)&hshL[w2][0];
        uint4 q0 = *(const uint4*)(hp + half * 16);
        uint4 q1 = *(const uint4*)(hp + half * 16 + 4);
        uint4 q2 = *(const uint4*)(hp + half * 16 + 8);
        uint4 q3 = *(const uint4*)(hp + half * 16 + 12);
        hu[0]=q0.x; hu[1]=q0.y; hu[2]=q0.z; hu[3]=q0.w;
        hu[4]=q1.x; hu[5]=q1.y; hu[6]=q1.z; hu[7]=q1.w;
        hu[8]=q2.x; hu[9]=q2.y; hu[10]=q2.z; hu[11]=q2.w;
        hu[12]=q3.x; hu[13]=q3.y; hu[14]=q3.z; hu[15]=q3.w;
      }
      float a0 = 0.f, a1 = 0.f, a2 = 0.f, a3 = 0.f;
      #pragma unroll
      for (int j = 0; j < 16; ++j) {
        a0 = fdot2f(hu[j], rr[0][j], a0);
        a1 = fdot2f(hu[j], rr[1][j], a1);
        a2 = fdot2f(hu[j], rr[2][j], a2);
        a3 = fdot2f(hu[j], rr[3][j], a3);
      }
      float s1 = 0.f, s2 = 0.f;
      #pragma unroll
      for (int j = 0; j < 16; ++j) {
        s1 = fdot2f(hu[j], one2, s1);
        s2 = fdot2f(hu[j], hu[j], s2);
      }
      if (k > 0) {   // deferred groupnorm of step k-1 (within chunk)
        float mu = s1 * (1.f / 32.f);
        float va = s2 * (1.f / 32.f) - mu * mu;
        float ov = xprev + (hprev - mu) * rsqrtf(va + 1e-5f) * gw;
        if (layer) psum += ov;
        else       xw[(k - 1) * XP + d] = ov;
      }

      f16x2 lo = __builtin_bit_cast(f16x2, pa[k]);
      f16x2 hi = __builtin_bit_cast(f16x2, pb[k]);
      float it = (float)lo[0] + a0, ft = (float)lo[1] + a1;
      float zt = (float)hi[0] + a2, ot = (float)hi[1] + a3;

      float mn = fmaxf(ft + mc, it);
      float iv = __expf(it - mn);
      float fv = __expf(ft + mc - mn);
      float zc = fminf(fmaxf(zt, -15.f), 15.f);
      float ez = __expf(2.f * zc);
      float tz = (ez - 1.f) * __builtin_amdgcn_rcpf(ez + 1.f);
      float cn = fv * cc + iv * tz;
      float nn = fv * nc + iv;
      float sg = __builtin_amdgcn_rcpf(1.f + __expf(-ot));
      float hn = sg * cn * __builtin_amdgcn_rcpf(nn);
      cc = cn; nc = nn; mc = mn;

      hshL[w2][lane] = (f16)hn;
      hprev = hn; xprev = xcur;
      if (k < CH - 1) xcur = xr[(k + 1) * XP + d];
    }
    // chunk epilogue: groupnorm of last row (row CH-1)
    {
      uint hu[16];
      const uint* hp = (const uint*)&hshL[w2][0];
      uint4 q0 = *(const uint4*)(hp + half * 16);
      uint4 q1 = *(const uint4*)(hp + half * 16 + 4);
      uint4 q2 = *(const uint4*)(hp + half * 16 + 8);
      uint4 q3 = *(const uint4*)(hp + half * 16 + 12);
      hu[0]=q0.x; hu[1]=q0.y; hu[2]=q0.z; hu[3]=q0.w;
      hu[4]=q1.x; hu[5]=q1.y; hu[6]=q1.z; hu[7]=q1.w;
      hu[8]=q2.x; hu[9]=q2.y; hu[10]=q2.z; hu[11]=q2.w;
      hu[12]=q3.x; hu[13]=q3.y; hu[14]=q3.z; hu[15]=q3.w;
      float s1 = 0.f, s2 = 0.f;
      #pragma unroll
      for (int j = 0; j < 16; ++j) {
        s1 = fdot2f(hu[j], one2, s1);
        s2 = fdot2f(hu[j], hu[j], s2);
      }
      float mu = s1 * (1.f / 32.f);
      float va = s2 * (1.f / 32.f) - mu * mu;
      float ov = xprev + (hprev - mu) * rsqrtf(va + 1e-5f) * gw;
      if (layer) psum += ov;
      else       xw[(CH - 1) * XP + d] = ov;
    }
  };

  // ---------------- software pipeline: 19 phases ----------------
  #pragma unroll 1
  for (int p = 0; p < NCH + 3; ++p) {
    if (wv < 2) {
      int c = p;       if (c < NCH)           gemm_do(c, 0, wv);
    } else if (wv < 4) {
      int c = p - 2;   if (c >= 0 && c < NCH) gemm_do(c, 1, wv & 1);
    } else if (wv < 6) {
      int c = p - 1;   if (c >= 0 && c < NCH) scan_do(c, 0);
    } else {
      int c = p - 3;   if (c >= 0 && c < NCH) scan_do(c, 1);
    }
    __syncthreads();
  }

  if (wv >= 6) {
    int d = (wv & 1) * 64 + lane;
    pooled[b * Dn + d] = psum * (1.f / 128.f);
  }
}

// ---------------- head: MLP on pooled [512][128] ----------------
__global__ __launch_bounds__(64) void k_head(const float* __restrict__ pooled,
                                             const float* __restrict__ w1,
                                             const float* __restrict__ b1,
                                             const float* __restrict__ w2,
                                             const float* __restrict__ b2,
                                             float* __restrict__ out) {
  int b = blockIdx.x;
  int tid = threadIdx.x;  // 64
  __shared__ float pool[128];
  __shared__ float hid[64];
  pool[tid]      = pooled[b * Dn + tid];
  pool[tid + 64] = pooled[b * Dn + tid + 64];
  __syncthreads();
  {
    float a = b1[tid];
    const float* wr = w1 + (size_t)tid * Dn;
    #pragma unroll 4
    for (int dd = 0; dd < Dn; ++dd) a += pool[dd] * wr[dd];
    hid[tid] = fmaxf(a, 0.f);
  }
  __syncthreads();
  if (tid < 2) {
    float a = b2[tid];
    const float* wr = w2 + tid * 64;
    #pragma unroll 4
    for (int j = 0; j < 64; ++j) a += hid[j] * wr[j];
    out[b * 2 + tid] = a;
  }
}

extern "C" void kernel_launch(void* const* d_in, const int* in_sizes, int n_in,
                              void* d_out, int out_size, void* d_ws, size_t ws_size,
                              hipStream_t stream) {
  const int*   ids  = (const int*)d_in[0];
  const float* emb  = (const float*)d_in[1];
  const float* ln_w = (const float*)d_in[2];
  const float* ln_b = (const float*)d_in[3];
  const float* Wg   = (const float*)d_in[4];
  const float* Rg   = (const float*)d_in[5];
  const float* bg   = (const float*)d_in[6];
  const float* gn_w = (const float*)d_in[7];
  const float* w1   = (const float*)d_in[8];
  const float* b1   = (const float*)d_in[9];
  const float* w2   = (const float*)d_in[10];
  const float* b2   = (const float*)d_in[11];
  float* out = (float*)d_out;

  char* ws = (char*)d_ws;
  f16*   WhF   = (f16*)ws;                      // 262,144 B
  f16*   RT    = (f16*)(ws + 262144);           //  65,536 B
  float* pooled= (float*)(ws + 262144 + 65536); // 262,144 B

  k_convert<<<192, 256, 0, stream>>>(Wg, Rg, WhF, RT);
  k_fused<<<512, 512, 0, stream>>>(ids, emb, ln_w, ln_b, WhF, RT, bg, gn_w, pooled);
  k_head<<<512, 64, 0, stream>>>(pooled, w1, b1, w2, b2, out);
}